// Round 7
// baseline (425.029 us; speedup 1.0000x reference)
//
#include <hip/hip_runtime.h>
#include <hip/hip_cooperative_groups.h>
#include <math.h>

namespace cg = cooperative_groups;

// ws header: hdr_i[0]=mw, hdr_i[1]=pad, hdr_i[2]=midx(k), hdr_f[3]=smin, hdr_f[4]=smax
// smin/smax are SAMPLED (clamped binning stays rank-exact; final bisection
// brackets from actual candidate values, so clamped outliers are safe).

__device__ __forceinline__ int bin_of(float x, float vmin, float scale, int NB) {
    int v = (int)((x - vmin) * scale);
    return v < 0 ? 0 : (v > NB - 1 ? NB - 1 : v);
}

// ===========================================================================
// Fused cooperative kernel: setup -> hist -> cdf+scatter -> query with 3
// grid syncs. All phases wave-granular; grid-stride loops everywhere.
// ===========================================================================
template<int NB>
__global__ void __launch_bounds__(256, 4) k_fused(
    const float* atten, const float* md,
    const float* w1, const float* b1, const float* w2, const float* b2,
    int* hdr_i, float* hdr_f,
    unsigned char* binIdx, unsigned short* tileCnt,
    unsigned short* F, float* bval, float* out,
    int T, int n_out, int nTot, int NTe, int NTr16)
{
    constexpr int VPL = NB / 64;
    cg::grid_group grid = cg::this_grid();
    __shared__ unsigned int hist[4][NB];
    __shared__ float smin4[4], smax4[4];

    const int tid = threadIdx.x;
    const int wave = tid >> 6, lane = tid & 63;
    const int nWavesTot = gridDim.x * 4;
    const int gw0 = blockIdx.x * 4 + wave;

    // ---------------- Phase A: setup (block 0 only) ----------------
    if (blockIdx.x == 0) {
        int strideS = nTot >> 10; if (strideS < 1) strideS = 1;
        float vmin = 3.0e38f, vmax = -3.0e38f;
        #pragma unroll
        for (int q = 0; q < 4; ++q) {
            int idx = (tid + q * 256) * strideS;
            if (idx < nTot) {
                float x = atten[idx];
                vmin = fminf(vmin, x); vmax = fmaxf(vmax, x);
            }
        }
        #pragma unroll
        for (int off = 1; off < 64; off <<= 1) {
            vmin = fminf(vmin, __shfl_xor(vmin, off));
            vmax = fmaxf(vmax, __shfl_xor(vmax, off));
        }
        if (lane == 0) { smin4[wave] = vmin; smax4[wave] = vmax; }
        __syncthreads();
        if (tid < 64) {
            float m1 = (lane < 4) ? smin4[lane] : 3.0e38f;
            float m2 = (lane < 4) ? smax4[lane] : -3.0e38f;
            #pragma unroll
            for (int off = 1; off < 4; off <<= 1) {
                m1 = fminf(m1, __shfl_xor(m1, off));
                m2 = fmaxf(m2, __shfl_xor(m2, off));
            }
            int samples = 0;
            if (lane < 32) {                 // lane = b*16 + j
                int b = lane >> 4, j = lane & 15;
                float acc = b1[j];
                #pragma unroll
                for (int f = 0; f < 8; ++f) acc += md[b * 8 + f] * w1[f * 16 + j];
                float h = fmaxf(acc, 0.0f);
                float p = h * w2[j];
                #pragma unroll
                for (int off = 1; off < 16; off <<= 1) p += __shfl_xor(p, off);
                float s = p + b2[0];
                float factor = 1.0f / (1.0f + expf(-s));
                float hours = 4.0f + factor * (48.0f - 4.0f);
                samples = (int)(hours * 360.0f);
            }
            #pragma unroll
            for (int off = 1; off < 64; off <<= 1) samples = max(samples, __shfl_xor(samples, off));
            int mw = min(samples, T);
            int want_even = (n_out == T + 1) ? 1 : 0;
            if ((((mw & 1) == 0) ? 1 : 0) != want_even) { if (mw < T) mw += 1; else mw -= 1; }
            if (mw < 1) mw = 1;
            if (lane == 0) {
                hdr_i[0] = mw;
                hdr_i[1] = mw >> 1;
                hdr_i[2] = (mw - 1) >> 1;
                hdr_f[3] = m1;
                hdr_f[4] = m2;
            }
        }
    }
    grid.sync();

    const float vmin = hdr_f[3], vmax = hdr_f[4];
    const float scale = (float)NB / fmaxf(vmax - vmin, 1e-10f);

    // ---------------- Phase B: binning + per-tile histogram ----------------
    for (int g = gw0; g < 2 * NTe; g += nWavesTot) {
        int b = g / NTe, tile = g - b * NTe;
        unsigned int* h = hist[wave];         // wave-private LDS region
        #pragma unroll
        for (int j = lane; j < NB; j += 64) h[j] = 0u;
        int t = tile * 64 + lane;
        if (t < T) {
            float x = atten[(size_t)b * T + t];
            int v = bin_of(x, vmin, scale, NB);
            binIdx[(size_t)b * T + t] = (unsigned char)v;
            atomicAdd(&h[v], 1u);
        }
        unsigned short* row = tileCnt + ((size_t)b * NTe + tile) * NB;
        #pragma unroll
        for (int j = lane; j < NB; j += 64) row[j] = (unsigned short)h[j];
    }
    grid.sync();

    // ---------------- Phase C: CDF + counting-sort scatter ----------------
    for (int g = gw0; g < 2 * NTr16; g += nWavesTot) {
        int b = g / NTr16, r = g - b * NTr16;
        int v0 = lane * VPL;
        int t0 = r * 16;
        int eb = t0 >> 6;
        int lead = t0 & 63;

        int bs[VPL], ts[VPL];
        if (VPL == 4) {
            const uint2* cb2 = (const uint2*)(tileCnt + (size_t)b * NTe * NB) + lane;
            const int stride = NB / 4;
            unsigned bax[8], bay[8], tax[8], tay[8];
            #pragma unroll
            for (int q = 0; q < 8; ++q) { bax[q] = bay[q] = tax[q] = tay[q] = 0u; }
            int rp = 0;
            for (; rp + 8 <= NTe; rp += 8) {
                #pragma unroll
                for (int q = 0; q < 8; ++q) {
                    uint2 u = cb2[(size_t)(rp + q) * stride];
                    bool inb = (rp + q) < eb;
                    tax[q] += u.x; tay[q] += u.y;
                    bax[q] += inb ? u.x : 0u; bay[q] += inb ? u.y : 0u;
                }
            }
            for (; rp < NTe; ++rp) {
                uint2 u = cb2[(size_t)rp * stride];
                bool inb = rp < eb;
                tax[0] += u.x; tay[0] += u.y;
                bax[0] += inb ? u.x : 0u; bay[0] += inb ? u.y : 0u;
            }
            unsigned bsx = 0, bsy = 0, tsx = 0, tsy = 0;
            #pragma unroll
            for (int q = 0; q < 8; ++q) { bsx += bax[q]; bsy += bay[q]; tsx += tax[q]; tsy += tay[q]; }
            bs[0] = (int)(bsx & 0xFFFFu); bs[1] = (int)(bsx >> 16);
            bs[2] = (int)(bsy & 0xFFFFu); bs[VPL - 1] = (int)(bsy >> 16);
            ts[0] = (int)(tsx & 0xFFFFu); ts[1] = (int)(tsx >> 16);
            ts[2] = (int)(tsy & 0xFFFFu); ts[VPL - 1] = (int)(tsy >> 16);
        } else {
            const unsigned short* cb = tileCnt + (size_t)b * NTe * NB + v0;
            int ba[8], taq[8];
            #pragma unroll
            for (int q = 0; q < 8; ++q) { ba[q] = 0; taq[q] = 0; }
            int rp = 0;
            for (; rp + 8 <= NTe; rp += 8) {
                #pragma unroll
                for (int q = 0; q < 8; ++q) {
                    int u = (int)cb[(size_t)(rp + q) * NB];
                    taq[q] += u;
                    ba[q] += ((rp + q) < eb) ? u : 0;
                }
            }
            for (; rp < NTe; ++rp) {
                int u = (int)cb[(size_t)rp * NB];
                taq[0] += u;
                ba[0] += (rp < eb) ? u : 0;
            }
            #pragma unroll
            for (int q = 1; q < 8; ++q) { ba[0] += ba[q]; taq[0] += taq[q]; }
            bs[0] = ba[0]; ts[0] = taq[0];
        }

        int c[VPL], totI[VPL];
        {
            int loc = 0;
            #pragma unroll
            for (int kk = 0; kk < VPL; ++kk) { loc += bs[kk]; c[kk] = loc; }
            int incl = loc;
            #pragma unroll
            for (int off = 1; off < 64; off <<= 1) {
                int n = __shfl_up(incl, off);
                if (lane >= off) incl += n;
            }
            int excl = incl - loc;
            #pragma unroll
            for (int kk = 0; kk < VPL; ++kk) c[kk] += excl;
        }
        {
            int loc = 0;
            #pragma unroll
            for (int kk = 0; kk < VPL; ++kk) { loc += ts[kk]; totI[kk] = loc; }
            int incl = loc;
            #pragma unroll
            for (int off = 1; off < 64; off <<= 1) {
                int n = __shfl_up(incl, off);
                if (lane >= off) incl += n;
            }
            int excl = incl - loc;
            #pragma unroll
            for (int kk = 0; kk < VPL; ++kk) totI[kk] += excl;
        }
        int totLeft = __shfl_up(totI[VPL - 1], 1);
        if (lane == 0) totLeft = 0;

        const unsigned char* bi = binIdx + (size_t)b * T;

        int myLead = (lane < lead && (eb * 64 + lane) < T) ? (int)bi[eb * 64 + lane] : 0;
        for (int j = 0; j < lead; ++j) {
            int bt = __shfl(myLead, j);
            #pragma unroll
            for (int kk = 0; kk < VPL; ++kk) c[kk] += (v0 + kk >= bt) ? 1 : 0;
        }

        int t1 = min(T + 1, t0 + 16);
        bool has16 = (lane < 16) && (t0 + lane) < T;
        int   myb = has16 ? (int)bi[t0 + lane] : 0;
        float myx = has16 ? atten[(size_t)b * T + t0 + lane] : 0.0f;
        unsigned short* Fb = F + (size_t)b * (T + 1) * NB;
        float* bvb = bval + (size_t)b * T;
        for (int t = t0; t < t1; ++t) {
            unsigned short* Ft = Fb + (size_t)t * NB + v0;
            if (VPL == 4) {
                uint2 pk;
                pk.x = (unsigned)c[0] | ((unsigned)c[1] << 16);
                pk.y = (unsigned)c[2] | ((unsigned)c[VPL - 1] << 16);
                *(uint2*)Ft = pk;
            } else {
                Ft[0] = (unsigned short)c[0];
            }
            if (t < T) {
                int j = t - t0;
                int bt = __shfl(myb, j);
                float xv = __shfl(myx, j);
                int cLeft = __shfl_up(c[VPL - 1], 1);
                if (lane == 0) cLeft = 0;
                int ow  = (VPL == 4) ? (bt >> 2) : bt;
                int lc  = (VPL == 4) ? (bt & 3) : 0;
                if (lane == ow) {
                    int prevc   = lc ? c[lc - 1]    : cLeft;
                    int within  = c[lc] - prevc;
                    int prevTot = lc ? totI[lc - 1] : totLeft;
                    bvb[prevTot + within] = xv;
                }
                #pragma unroll
                for (int kk = 0; kk < VPL; ++kk) c[kk] += (v0 + kk >= bt) ? 1 : 0;
            }
        }
    }
    grid.sync();

    // ---------------- Phase D: wave-per-output query ----------------
    const int mw = hdr_i[0], pad = hdr_i[1], k = hdr_i[2];
    for (int g = gw0; g < 2 * n_out; g += nWavesTot) {
        int b = g / n_out, o = g - b * n_out;

        int lo_t = o - pad;
        int ta = max(lo_t, 0);
        int tb = min(lo_t + mw, T);
        int L  = ta - lo_t;
        int Rr = lo_t + mw - tb;

        const float* xb = atten + (size_t)b * T;
        float x0 = xb[0], xT = xb[T - 1];
        int b0 = bin_of(x0, vmin, scale, NB);
        int bT = bin_of(xT, vmin, scale, NB);

        const unsigned short* Fb = F + (size_t)b * (T + 1) * NB;
        int fa[VPL], fb[VPL];
        {
            const unsigned short* pa = Fb + (size_t)ta * NB + lane * VPL;
            const unsigned short* pb = Fb + (size_t)tb * NB + lane * VPL;
            if (VPL == 4) {
                uint2 ua = *(const uint2*)pa;
                fa[0] = (int)(ua.x & 0xFFFFu); fa[1] = (int)(ua.x >> 16);
                fa[2] = (int)(ua.y & 0xFFFFu); fa[VPL - 1] = (int)(ua.y >> 16);
                uint2 ub = *(const uint2*)pb;
                fb[0] = (int)(ub.x & 0xFFFFu); fb[1] = (int)(ub.x >> 16);
                fb[2] = (int)(ub.y & 0xFFFFu); fb[VPL - 1] = (int)(ub.y >> 16);
            } else {
                fa[0] = (int)pa[0]; fb[0] = (int)pb[0];
            }
        }

        int kk = k + 1;
        int w[VPL];
        #pragma unroll
        for (int j = 0; j < VPL; ++j) {
            int v = lane * VPL + j;
            w[j] = fb[j] - fa[j] + (b0 <= v ? L : 0) + (bT <= v ? Rr : 0);
        }
        unsigned long long m = __ballot(w[VPL - 1] >= kk);
        int ll = (int)__ffsll(m) - 1;

        int wj[VPL], faj[VPL], fbj[VPL];
        #pragma unroll
        for (int j = 0; j < VPL; ++j) {
            wj[j]  = __shfl(w[j], ll);
            faj[j] = __shfl(fa[j], ll);
            fbj[j] = __shfl(fb[j], ll);
        }
        int wprevL  = __shfl(w[VPL - 1], ll - 1);
        int faPrevL = __shfl(fa[VPL - 1], ll - 1);
        int fbPrevL = __shfl(fb[VPL - 1], ll - 1);
        if (ll == 0) { wprevL = 0; faPrevL = 0; fbPrevL = 0; }

        int jj = VPL - 1;
        #pragma unroll
        for (int j = VPL - 1; j >= 0; --j) if (wj[j] >= kk) jj = j;
        int bsel = ll * VPL + jj;
        int wprev = jj > 0 ? wj[jj - 1] : wprevL;
        int faSel = faj[jj], fbSel = fbj[jj];
        int pA = jj > 0 ? faj[jj - 1] : faPrevL;
        int pB = jj > 0 ? fbj[jj - 1] : fbPrevL;

        int kp = k - wprev;
        int withinA = faSel - pA;
        int cntw = (fbSel - pB) - withinA;
        int s0 = bsel ? (int)Fb[(size_t)T * NB + bsel - 1] : 0;
        int j0 = s0 + withinA;
        int j1e = j0 + cntw;

        int Lc = (b0 == bsel) ? L : 0;
        int Rc = (bT == bsel) ? Rr : 0;

        const float* bv = bval + (size_t)b * T;

        const int CAND = 4;
        float rr[CAND];
        bool reg = (cntw <= 64 * CAND);
        float cmin = 3.0e38f, cmax = -3.0e38f;
        if (reg) {
            #pragma unroll
            for (int q = 0; q < CAND; ++q) {
                int idx = j0 + lane + q * 64;
                if (idx < j1e) {
                    float v = bv[idx];
                    rr[q] = v;
                    cmin = fminf(cmin, v); cmax = fmaxf(cmax, v);
                } else {
                    rr[q] = 3.0e38f;
                }
            }
        } else {
            for (int j = j0 + lane; j < j1e; j += 64) {
                float v = bv[j];
                cmin = fminf(cmin, v); cmax = fmaxf(cmax, v);
            }
        }
        #pragma unroll
        for (int off = 1; off < 64; off <<= 1) {
            cmin = fminf(cmin, __shfl_xor(cmin, off));
            cmax = fmaxf(cmax, __shfl_xor(cmax, off));
        }
        if (Lc > 0) { cmin = fminf(cmin, x0); cmax = fmaxf(cmax, x0); }
        if (Rc > 0) { cmin = fminf(cmin, xT); cmax = fmaxf(cmax, xT); }

        float vlo = cmin, vhi = cmax;
        int need = kp + 1;
        for (int it = 0; it < 14; ++it) {
            float vm = 0.5f * (vlo + vhi);
            int cnt = ((x0 < vm) ? Lc : 0) + ((xT < vm) ? Rc : 0);
            if (reg) {
                #pragma unroll
                for (int q = 0; q < CAND; ++q)
                    cnt += __popcll(__ballot(rr[q] < vm));
            } else {
                int my = 0;
                for (int j = j0 + lane; j < j1e; j += 64) my += (bv[j] < vm) ? 1 : 0;
                #pragma unroll
                for (int off = 1; off < 64; off <<= 1) my += __shfl_xor(my, off);
                cnt += my;
            }
            if (cnt >= need) vhi = vm; else vlo = vm;
        }
        if (lane == 0) out[(size_t)b * n_out + o] = 0.5f * (vlo + vhi);
    }
}

// ===========================================================================
// Legacy pipeline kernels (fallback if cooperative launch is unavailable).
// ===========================================================================
__global__ void __launch_bounds__(256) k_setup(
    const float* __restrict__ atten, const float* __restrict__ md,
    const float* __restrict__ w1, const float* __restrict__ b1,
    const float* __restrict__ w2, const float* __restrict__ b2,
    int* __restrict__ hdr_i, float* __restrict__ hdr_f,
    int T, int n_out, int nTot)
{
    __shared__ float smin[4], smax[4];
    int tid = threadIdx.x;
    int strideS = nTot >> 10; if (strideS < 1) strideS = 1;
    float vmin = 3.0e38f, vmax = -3.0e38f;
    #pragma unroll
    for (int q = 0; q < 4; ++q) {
        int idx = (tid + q * 256) * strideS;
        if (idx < nTot) {
            float x = atten[idx];
            vmin = fminf(vmin, x); vmax = fmaxf(vmax, x);
        }
    }
    #pragma unroll
    for (int off = 1; off < 64; off <<= 1) {
        vmin = fminf(vmin, __shfl_xor(vmin, off));
        vmax = fmaxf(vmax, __shfl_xor(vmax, off));
    }
    if ((tid & 63) == 0) { smin[tid >> 6] = vmin; smax[tid >> 6] = vmax; }
    __syncthreads();
    if (tid < 64) {
        int lane = tid;
        float m1 = (lane < 4) ? smin[lane] : 3.0e38f;
        float m2 = (lane < 4) ? smax[lane] : -3.0e38f;
        #pragma unroll
        for (int off = 1; off < 4; off <<= 1) {
            m1 = fminf(m1, __shfl_xor(m1, off));
            m2 = fmaxf(m2, __shfl_xor(m2, off));
        }
        int samples = 0;
        if (lane < 32) {
            int b = lane >> 4, j = lane & 15;
            float acc = b1[j];
            #pragma unroll
            for (int f = 0; f < 8; ++f) acc += md[b * 8 + f] * w1[f * 16 + j];
            float h = fmaxf(acc, 0.0f);
            float p = h * w2[j];
            #pragma unroll
            for (int off = 1; off < 16; off <<= 1) p += __shfl_xor(p, off);
            float s = p + b2[0];
            float factor = 1.0f / (1.0f + expf(-s));
            float hours = 4.0f + factor * (48.0f - 4.0f);
            samples = (int)(hours * 360.0f);
        }
        #pragma unroll
        for (int off = 1; off < 64; off <<= 1) samples = max(samples, __shfl_xor(samples, off));
        int mw = min(samples, T);
        int want_even = (n_out == T + 1) ? 1 : 0;
        if ((((mw & 1) == 0) ? 1 : 0) != want_even) { if (mw < T) mw += 1; else mw -= 1; }
        if (mw < 1) mw = 1;
        if (lane == 0) {
            hdr_i[0] = mw; hdr_i[1] = mw >> 1; hdr_i[2] = (mw - 1) >> 1;
            hdr_f[3] = m1; hdr_f[4] = m2;
        }
    }
}

template<int NB>
__global__ void __launch_bounds__(256) k_hist(
    const float* __restrict__ atten, unsigned char* __restrict__ binIdx,
    unsigned short* __restrict__ tileCnt, const float* __restrict__ hdr_f,
    int T, int NTe)
{
    __shared__ unsigned int hist[4][NB];
    int wave = threadIdx.x >> 6;
    int lane = threadIdx.x & 63;
    int g = blockIdx.x * 4 + wave;
    bool valid = g < 2 * NTe;
    int b = g / NTe, tile = g - b * NTe;

    #pragma unroll
    for (int j = lane; j < NB; j += 64) hist[wave][j] = 0;
    __syncthreads();

    int t = tile * 64 + lane;
    if (valid && t < T) {
        float vmin = hdr_f[3], vmax = hdr_f[4];
        float scale = (float)NB / fmaxf(vmax - vmin, 1e-10f);
        float x = atten[(size_t)b * T + t];
        int v = bin_of(x, vmin, scale, NB);
        binIdx[(size_t)b * T + t] = (unsigned char)v;
        atomicAdd(&hist[wave][v], 1u);
    }
    __syncthreads();
    if (valid) {
        unsigned short* row = tileCnt + ((size_t)b * NTe + tile) * NB;
        #pragma unroll
        for (int j = lane; j < NB; j += 64) row[j] = (unsigned short)hist[wave][j];
    }
}

template<int NB>
__global__ void __launch_bounds__(64) k_cdf_scatter(
    const unsigned char* __restrict__ binIdx, const unsigned short* __restrict__ tileCnt,
    const float* __restrict__ atten,
    unsigned short* __restrict__ F, float* __restrict__ bval,
    int T, int NTe, int NTr16)
{
    constexpr int VPL = NB / 64;
    int blk = blockIdx.x;
    int b = blk / NTr16, r = blk - b * NTr16;
    int lane = threadIdx.x;
    int v0 = lane * VPL;
    int t0 = r * 16;
    int eb = t0 >> 6;
    int lead = t0 & 63;

    int bs[VPL], ts[VPL];
    if (VPL == 4) {
        const uint2* cb2 = (const uint2*)(tileCnt + (size_t)b * NTe * NB) + lane;
        const int stride = NB / 4;
        unsigned bax[8], bay[8], tax[8], tay[8];
        #pragma unroll
        for (int q = 0; q < 8; ++q) { bax[q] = bay[q] = tax[q] = tay[q] = 0u; }
        int rp = 0;
        for (; rp + 8 <= NTe; rp += 8) {
            #pragma unroll
            for (int q = 0; q < 8; ++q) {
                uint2 u = cb2[(size_t)(rp + q) * stride];
                bool inb = (rp + q) < eb;
                tax[q] += u.x; tay[q] += u.y;
                bax[q] += inb ? u.x : 0u; bay[q] += inb ? u.y : 0u;
            }
        }
        for (; rp < NTe; ++rp) {
            uint2 u = cb2[(size_t)rp * stride];
            bool inb = rp < eb;
            tax[0] += u.x; tay[0] += u.y;
            bax[0] += inb ? u.x : 0u; bay[0] += inb ? u.y : 0u;
        }
        unsigned bsx = 0, bsy = 0, tsx = 0, tsy = 0;
        #pragma unroll
        for (int q = 0; q < 8; ++q) { bsx += bax[q]; bsy += bay[q]; tsx += tax[q]; tsy += tay[q]; }
        bs[0] = (int)(bsx & 0xFFFFu); bs[1] = (int)(bsx >> 16);
        bs[2] = (int)(bsy & 0xFFFFu); bs[VPL - 1] = (int)(bsy >> 16);
        ts[0] = (int)(tsx & 0xFFFFu); ts[1] = (int)(tsx >> 16);
        ts[2] = (int)(tsy & 0xFFFFu); ts[VPL - 1] = (int)(tsy >> 16);
    } else {
        const unsigned short* cb = tileCnt + (size_t)b * NTe * NB + v0;
        int ba[8], taq[8];
        #pragma unroll
        for (int q = 0; q < 8; ++q) { ba[q] = 0; taq[q] = 0; }
        int rp = 0;
        for (; rp + 8 <= NTe; rp += 8) {
            #pragma unroll
            for (int q = 0; q < 8; ++q) {
                int u = (int)cb[(size_t)(rp + q) * NB];
                taq[q] += u;
                ba[q] += ((rp + q) < eb) ? u : 0;
            }
        }
        for (; rp < NTe; ++rp) {
            int u = (int)cb[(size_t)rp * NB];
            taq[0] += u;
            ba[0] += (rp < eb) ? u : 0;
        }
        #pragma unroll
        for (int q = 1; q < 8; ++q) { ba[0] += ba[q]; taq[0] += taq[q]; }
        bs[0] = ba[0]; ts[0] = taq[0];
    }

    int c[VPL], totI[VPL];
    {
        int loc = 0;
        #pragma unroll
        for (int kk = 0; kk < VPL; ++kk) { loc += bs[kk]; c[kk] = loc; }
        int incl = loc;
        #pragma unroll
        for (int off = 1; off < 64; off <<= 1) {
            int n = __shfl_up(incl, off);
            if (lane >= off) incl += n;
        }
        int excl = incl - loc;
        #pragma unroll
        for (int kk = 0; kk < VPL; ++kk) c[kk] += excl;
    }
    {
        int loc = 0;
        #pragma unroll
        for (int kk = 0; kk < VPL; ++kk) { loc += ts[kk]; totI[kk] = loc; }
        int incl = loc;
        #pragma unroll
        for (int off = 1; off < 64; off <<= 1) {
            int n = __shfl_up(incl, off);
            if (lane >= off) incl += n;
        }
        int excl = incl - loc;
        #pragma unroll
        for (int kk = 0; kk < VPL; ++kk) totI[kk] += excl;
    }
    int totLeft = __shfl_up(totI[VPL - 1], 1);
    if (lane == 0) totLeft = 0;

    const unsigned char* bi = binIdx + (size_t)b * T;

    int myLead = (lane < lead && (eb * 64 + lane) < T) ? (int)bi[eb * 64 + lane] : 0;
    for (int j = 0; j < lead; ++j) {
        int bt = __shfl(myLead, j);
        #pragma unroll
        for (int kk = 0; kk < VPL; ++kk) c[kk] += (v0 + kk >= bt) ? 1 : 0;
    }

    int t1 = min(T + 1, t0 + 16);
    bool has16 = (lane < 16) && (t0 + lane) < T;
    int   myb = has16 ? (int)bi[t0 + lane] : 0;
    float myx = has16 ? atten[(size_t)b * T + t0 + lane] : 0.0f;
    unsigned short* Fb = F + (size_t)b * (T + 1) * NB;
    float* bvb = bval + (size_t)b * T;
    for (int t = t0; t < t1; ++t) {
        unsigned short* Ft = Fb + (size_t)t * NB + v0;
        if (VPL == 4) {
            uint2 pk;
            pk.x = (unsigned)c[0] | ((unsigned)c[1] << 16);
            pk.y = (unsigned)c[2] | ((unsigned)c[VPL - 1] << 16);
            *(uint2*)Ft = pk;
        } else {
            Ft[0] = (unsigned short)c[0];
        }
        if (t < T) {
            int j = t - t0;
            int bt = __shfl(myb, j);
            float xv = __shfl(myx, j);
            int cLeft = __shfl_up(c[VPL - 1], 1);
            if (lane == 0) cLeft = 0;
            int ow  = (VPL == 4) ? (bt >> 2) : bt;
            int lc  = (VPL == 4) ? (bt & 3) : 0;
            if (lane == ow) {
                int prevc   = lc ? c[lc - 1]    : cLeft;
                int within  = c[lc] - prevc;
                int prevTot = lc ? totI[lc - 1] : totLeft;
                bvb[prevTot + within] = xv;
            }
            #pragma unroll
            for (int kk = 0; kk < VPL; ++kk) c[kk] += (v0 + kk >= bt) ? 1 : 0;
        }
    }
}

template<int NB>
__global__ void __launch_bounds__(256) k_query(
    const float* __restrict__ atten, const unsigned short* __restrict__ F,
    const float* __restrict__ bval,
    const int* __restrict__ hdr_i, const float* __restrict__ hdr_f,
    float* __restrict__ out, int T, int n_out)
{
    constexpr int VPL = NB / 64;
    int wid = (blockIdx.x * 256 + threadIdx.x) >> 6;
    int lane = threadIdx.x & 63;
    if (wid >= 2 * n_out) return;
    int b = wid / n_out, o = wid - b * n_out;

    int mw = hdr_i[0], pad = hdr_i[1], k = hdr_i[2];
    float vmin = hdr_f[3], vmax = hdr_f[4];
    float scale = (float)NB / fmaxf(vmax - vmin, 1e-10f);

    int lo_t = o - pad;
    int ta = max(lo_t, 0);
    int tb = min(lo_t + mw, T);
    int L  = ta - lo_t;
    int Rr = lo_t + mw - tb;

    const float* xb = atten + (size_t)b * T;
    float x0 = xb[0], xT = xb[T - 1];
    int b0 = bin_of(x0, vmin, scale, NB);
    int bT = bin_of(xT, vmin, scale, NB);

    const unsigned short* Fb = F + (size_t)b * (T + 1) * NB;
    int fa[VPL], fb[VPL];
    {
        const unsigned short* pa = Fb + (size_t)ta * NB + lane * VPL;
        const unsigned short* pb = Fb + (size_t)tb * NB + lane * VPL;
        if (VPL == 4) {
            uint2 ua = *(const uint2*)pa;
            fa[0] = (int)(ua.x & 0xFFFFu); fa[1] = (int)(ua.x >> 16);
            fa[2] = (int)(ua.y & 0xFFFFu); fa[VPL - 1] = (int)(ua.y >> 16);
            uint2 ub = *(const uint2*)pb;
            fb[0] = (int)(ub.x & 0xFFFFu); fb[1] = (int)(ub.x >> 16);
            fb[2] = (int)(ub.y & 0xFFFFu); fb[VPL - 1] = (int)(ub.y >> 16);
        } else {
            fa[0] = (int)pa[0]; fb[0] = (int)pb[0];
        }
    }

    int kk = k + 1;
    int w[VPL];
    #pragma unroll
    for (int j = 0; j < VPL; ++j) {
        int v = lane * VPL + j;
        w[j] = fb[j] - fa[j] + (b0 <= v ? L : 0) + (bT <= v ? Rr : 0);
    }
    unsigned long long m = __ballot(w[VPL - 1] >= kk);
    int ll = (int)__ffsll(m) - 1;

    int wj[VPL], faj[VPL], fbj[VPL];
    #pragma unroll
    for (int j = 0; j < VPL; ++j) {
        wj[j]  = __shfl(w[j], ll);
        faj[j] = __shfl(fa[j], ll);
        fbj[j] = __shfl(fb[j], ll);
    }
    int wprevL  = __shfl(w[VPL - 1], ll - 1);
    int faPrevL = __shfl(fa[VPL - 1], ll - 1);
    int fbPrevL = __shfl(fb[VPL - 1], ll - 1);
    if (ll == 0) { wprevL = 0; faPrevL = 0; fbPrevL = 0; }

    int jj = VPL - 1;
    #pragma unroll
    for (int j = VPL - 1; j >= 0; --j) if (wj[j] >= kk) jj = j;
    int bsel = ll * VPL + jj;
    int wprev = jj > 0 ? wj[jj - 1] : wprevL;
    int faSel = faj[jj], fbSel = fbj[jj];
    int pA = jj > 0 ? faj[jj - 1] : faPrevL;
    int pB = jj > 0 ? fbj[jj - 1] : fbPrevL;

    int kp = k - wprev;
    int withinA = faSel - pA;
    int cntw = (fbSel - pB) - withinA;
    int s0 = bsel ? (int)Fb[(size_t)T * NB + bsel - 1] : 0;
    int j0 = s0 + withinA;
    int j1e = j0 + cntw;

    int Lc = (b0 == bsel) ? L : 0;
    int Rc = (bT == bsel) ? Rr : 0;

    const float* bv = bval + (size_t)b * T;

    const int CAND = 4;
    float rr[CAND];
    bool reg = (cntw <= 64 * CAND);
    float cmin = 3.0e38f, cmax = -3.0e38f;
    if (reg) {
        #pragma unroll
        for (int q = 0; q < CAND; ++q) {
            int idx = j0 + lane + q * 64;
            if (idx < j1e) {
                float v = bv[idx];
                rr[q] = v;
                cmin = fminf(cmin, v); cmax = fmaxf(cmax, v);
            } else {
                rr[q] = 3.0e38f;
            }
        }
    } else {
        for (int j = j0 + lane; j < j1e; j += 64) {
            float v = bv[j];
            cmin = fminf(cmin, v); cmax = fmaxf(cmax, v);
        }
    }
    #pragma unroll
    for (int off = 1; off < 64; off <<= 1) {
        cmin = fminf(cmin, __shfl_xor(cmin, off));
        cmax = fmaxf(cmax, __shfl_xor(cmax, off));
    }
    if (Lc > 0) { cmin = fminf(cmin, x0); cmax = fmaxf(cmax, x0); }
    if (Rc > 0) { cmin = fminf(cmin, xT); cmax = fmaxf(cmax, xT); }

    float vlo = cmin, vhi = cmax;
    int need = kp + 1;
    for (int it = 0; it < 14; ++it) {
        float vm = 0.5f * (vlo + vhi);
        int cnt = ((x0 < vm) ? Lc : 0) + ((xT < vm) ? Rc : 0);
        if (reg) {
            #pragma unroll
            for (int q = 0; q < CAND; ++q)
                cnt += __popcll(__ballot(rr[q] < vm));
        } else {
            int my = 0;
            for (int j = j0 + lane; j < j1e; j += 64) my += (bv[j] < vm) ? 1 : 0;
            #pragma unroll
            for (int off = 1; off < 64; off <<= 1) my += __shfl_xor(my, off);
            cnt += my;
        }
        if (cnt >= need) vhi = vm; else vlo = vm;
    }
    if (lane == 0) out[(size_t)b * n_out + o] = 0.5f * (vlo + vhi);
}

__global__ void __launch_bounds__(256) k_fallback(
    const float* __restrict__ atten, const int* __restrict__ hdr_i,
    float* __restrict__ out, int T, int n_out)
{
    int wave = threadIdx.x >> 6;
    int lane = threadIdx.x & 63;
    int gid = blockIdx.x * 4 + wave;
    if (gid >= 2 * n_out) return;
    int b = gid / n_out;
    int o = gid - b * n_out;
    int mw = hdr_i[0], pad = hdr_i[1], k = hdr_i[2];
    const float* xb = atten + (size_t)b * T;
    int lo_t = o - pad;
    float lo = 3.0e38f, hi = -3.0e38f;
    for (int i = lane; i < mw; i += 64) {
        int t = lo_t + i;
        t = t < 0 ? 0 : (t >= T ? T - 1 : t);
        float x = xb[t];
        lo = fminf(lo, x); hi = fmaxf(hi, x);
    }
    #pragma unroll
    for (int off = 1; off < 64; off <<= 1) {
        lo = fminf(lo, __shfl_xor(lo, off));
        hi = fmaxf(hi, __shfl_xor(hi, off));
    }
    for (int it = 0; it < 26; ++it) {
        float vm = 0.5f * (lo + hi);
        int c = 0;
        for (int i = lane; i < mw; i += 64) {
            int t = lo_t + i;
            t = t < 0 ? 0 : (t >= T ? T - 1 : t);
            c += (xb[t] < vm) ? 1 : 0;
        }
        #pragma unroll
        for (int off = 1; off < 64; off <<= 1) c += __shfl_xor(c, off);
        if (c >= k + 1) hi = vm; else lo = vm;
    }
    if (lane == 0) out[(size_t)b * n_out + o] = 0.5f * (lo + hi);
}

// ---------------------------------------------------------------------------
struct Plan { size_t oBin, oCnt, oF, oV, total; };
static Plan make_plan(int NB, int nTot, int T, int NTe) {
    auto a64 = [](size_t x) { return (x + 63) & ~(size_t)63; };
    Plan p;
    size_t off = 64;
    p.oBin = off; off = a64(off + (size_t)nTot);
    p.oCnt = off; off = a64(off + (size_t)2 * NTe * NB * 2);
    p.oF   = off; off = a64(off + (size_t)2 * (T + 1) * NB * 2);
    p.oV   = off; off = a64(off + (size_t)nTot * 4);
    p.total = off;
    return p;
}

template<int NB>
static void run_pipeline(const float* atten, const float* md,
                         const float* w1, const float* b1,
                         const float* w2, const float* b2,
                         char* ws, const Plan& p,
                         int* hdr_i, float* hdr_f, float* out,
                         int T, int n_out, int nTot, int NTe,
                         hipStream_t stream)
{
    unsigned char*  binIdx  = (unsigned char*)(ws + p.oBin);
    unsigned short* tileCnt = (unsigned short*)(ws + p.oCnt);
    unsigned short* F       = (unsigned short*)(ws + p.oF);
    float*          bval    = (float*)(ws + p.oV);
    int NTr16 = (T + 1 + 15) / 16;

    // Try the single cooperative fused kernel first.
    const float* a_atten = atten; const float* a_md = md;
    const float* a_w1 = w1; const float* a_b1 = b1;
    const float* a_w2 = w2; const float* a_b2 = b2;
    int* a_hdr_i = hdr_i; float* a_hdr_f = hdr_f;
    unsigned char* a_bin = binIdx; unsigned short* a_cnt = tileCnt;
    unsigned short* a_F = F; float* a_bval = bval; float* a_out = out;
    int vT = T, vn_out = n_out, vnTot = nTot, vNTe = NTe, vNTr16 = NTr16;
    void* args[] = { &a_atten, &a_md, &a_w1, &a_b1, &a_w2, &a_b2,
                     &a_hdr_i, &a_hdr_f, &a_bin, &a_cnt, &a_F, &a_bval, &a_out,
                     &vT, &vn_out, &vnTot, &vNTe, &vNTr16 };
    hipError_t e = hipLaunchCooperativeKernel(
        (const void*)&k_fused<NB>, dim3(1024), dim3(256), args, 0, stream);
    if (e == hipSuccess) return;
    (void)hipGetLastError();   // clear sticky error; fall back to pipeline

    k_setup<<<dim3(1), dim3(256), 0, stream>>>(atten, md, w1, b1, w2, b2,
                                               hdr_i, hdr_f, T, n_out, nTot);
    int histBlocks = (2 * NTe + 3) / 4;
    k_hist<NB><<<dim3(histBlocks), dim3(256), 0, stream>>>(atten, binIdx, tileCnt, hdr_f, T, NTe);
    k_cdf_scatter<NB><<<dim3(2 * NTr16), dim3(64), 0, stream>>>(binIdx, tileCnt, atten, F, bval, T, NTe, NTr16);
    int nWaves = 2 * n_out;
    k_query<NB><<<dim3((nWaves + 3) / 4), dim3(256), 0, stream>>>(atten, F, bval, hdr_i, hdr_f, out, T, n_out);
}

extern "C" void kernel_launch(void* const* d_in, const int* in_sizes, int n_in,
                              void* d_out, int out_size, void* d_ws, size_t ws_size,
                              hipStream_t stream)
{
    const float* atten = (const float*)d_in[0];
    const float* md    = (const float*)d_in[1];
    const float* w1    = (const float*)d_in[2];
    const float* b1    = (const float*)d_in[3];
    const float* w2    = (const float*)d_in[4];
    const float* b2    = (const float*)d_in[5];
    float* out = (float*)d_out;

    const int B = 2;
    const int nTot  = in_sizes[0];
    const int T     = nTot / B;
    const int n_out = out_size / B;
    const int NTe = (T + 63) / 64;

    char* ws = (char*)d_ws;
    int*   hdr_i = (int*)ws;
    float* hdr_f = (float*)ws;

    Plan p256 = make_plan(256, nTot, T, NTe);
    Plan p64  = make_plan(64,  nTot, T, NTe);
    if (ws_size >= p256.total) {
        run_pipeline<256>(atten, md, w1, b1, w2, b2, ws, p256, hdr_i, hdr_f, out,
                          T, n_out, nTot, NTe, stream);
    } else if (ws_size >= p64.total) {
        run_pipeline<64>(atten, md, w1, b1, w2, b2, ws, p64, hdr_i, hdr_f, out,
                         T, n_out, nTot, NTe, stream);
    } else {
        k_setup<<<dim3(1), dim3(256), 0, stream>>>(atten, md, w1, b1, w2, b2,
                                                   hdr_i, hdr_f, T, n_out, nTot);
        int blocks = (2 * n_out + 3) / 4;
        k_fallback<<<dim3(blocks), dim3(256), 0, stream>>>(atten, hdr_i, out, T, n_out);
    }
}

// Round 8
// 109.380 us; speedup vs baseline: 3.8858x; 3.8858x over previous
//
#include <hip/hip_runtime.h>
#include <math.h>

// No cross-kernel header: every block that needs setup recomputes it
// deterministically (identical sampled min/max; identical MLP) — bit-exact
// across blocks, so no grid-wide communication is required.
// LESSON (R7): cooperative grid.sync() costs ~100us/barrier on MI355X
// (cross-XCD fence). Kernel boundaries are the cheap barrier.

__device__ __forceinline__ int bin_of(float x, float vmin, float scale, int NB) {
    int v = (int)((x - vmin) * scale);
    return v < 0 ? 0 : (v > NB - 1 ? NB - 1 : v);
}

// Deterministic sampled min/max over 1024 strided points. All 256 threads
// participate; result valid in ALL threads after return. Uses 8 floats of LDS.
__device__ __forceinline__ void sampled_minmax_256(
    const float* __restrict__ atten, int nTot, float* sred /* [8] LDS */,
    float& m1, float& m2)
{
    int tid = threadIdx.x;
    int wave = tid >> 6, lane = tid & 63;
    int strideS = nTot >> 10; if (strideS < 1) strideS = 1;
    float vmn = 3.0e38f, vmx = -3.0e38f;
    #pragma unroll
    for (int q = 0; q < 4; ++q) {
        int idx = (tid + q * 256) * strideS;
        if (idx < nTot) {
            float x = atten[idx];
            vmn = fminf(vmn, x); vmx = fmaxf(vmx, x);
        }
    }
    #pragma unroll
    for (int off = 1; off < 64; off <<= 1) {
        vmn = fminf(vmn, __shfl_xor(vmn, off));
        vmx = fmaxf(vmx, __shfl_xor(vmx, off));
    }
    if (lane == 0) { sred[wave] = vmn; sred[4 + wave] = vmx; }
    __syncthreads();
    m1 = fminf(fminf(sred[0], sred[1]), fminf(sred[2], sred[3]));
    m2 = fmaxf(fmaxf(sred[4], sred[5]), fmaxf(sred[6], sred[7]));
}

// ---------------------------------------------------------------------------
// K1: binning + per-tile histogram (4 element-tiles per 256-thr block).
// Each block recomputes the sampled range itself.
// ---------------------------------------------------------------------------
template<int NB>
__global__ void __launch_bounds__(256) k_hist(
    const float* __restrict__ atten, unsigned char* __restrict__ binIdx,
    unsigned short* __restrict__ tileCnt, int T, int NTe, int nTot)
{
    __shared__ unsigned int hist[4][NB];
    __shared__ float sred[8];
    float m1, m2;
    sampled_minmax_256(atten, nTot, sred, m1, m2);
    float scale = (float)NB / fmaxf(m2 - m1, 1e-10f);

    int wave = threadIdx.x >> 6;
    int lane = threadIdx.x & 63;
    int g = blockIdx.x * 4 + wave;
    bool valid = g < 2 * NTe;
    int b = g / NTe, tile = g - b * NTe;

    unsigned int* h = hist[wave];            // wave-private: no block sync needed
    #pragma unroll
    for (int j = lane; j < NB; j += 64) h[j] = 0u;

    int t = tile * 64 + lane;
    if (valid && t < T) {
        float x = atten[(size_t)b * T + t];
        int v = bin_of(x, m1, scale, NB);
        binIdx[(size_t)b * T + t] = (unsigned char)v;
        atomicAdd(&h[v], 1u);
    }
    if (valid) {
        unsigned short* row = tileCnt + ((size_t)b * NTe + tile) * NB;
        #pragma unroll
        for (int j = lane; j < NB; j += 64) row[j] = (unsigned short)h[j];
    }
}

// ---------------------------------------------------------------------------
// K2: fused CDF writer + counting-sort scatter. 16-record tiles, 64 thr.
// ILP-8 packed-u16 prefix (R5 fix). Unchanged from R6.
// ---------------------------------------------------------------------------
template<int NB>
__global__ void __launch_bounds__(64) k_cdf_scatter(
    const unsigned char* __restrict__ binIdx, const unsigned short* __restrict__ tileCnt,
    const float* __restrict__ atten,
    unsigned short* __restrict__ F, float* __restrict__ bval,
    int T, int NTe, int NTr16)
{
    constexpr int VPL = NB / 64;
    int blk = blockIdx.x;
    int b = blk / NTr16, r = blk - b * NTr16;
    int lane = threadIdx.x;
    int v0 = lane * VPL;
    int t0 = r * 16;
    int eb = t0 >> 6;
    int lead = t0 & 63;

    int bs[VPL], ts[VPL];
    if (VPL == 4) {
        const uint2* cb2 = (const uint2*)(tileCnt + (size_t)b * NTe * NB) + lane;
        const int stride = NB / 4;
        unsigned bax[8], bay[8], tax[8], tay[8];
        #pragma unroll
        for (int q = 0; q < 8; ++q) { bax[q] = bay[q] = tax[q] = tay[q] = 0u; }
        int rp = 0;
        for (; rp + 8 <= NTe; rp += 8) {
            #pragma unroll
            for (int q = 0; q < 8; ++q) {
                uint2 u = cb2[(size_t)(rp + q) * stride];
                bool inb = (rp + q) < eb;
                tax[q] += u.x; tay[q] += u.y;
                bax[q] += inb ? u.x : 0u; bay[q] += inb ? u.y : 0u;
            }
        }
        for (; rp < NTe; ++rp) {
            uint2 u = cb2[(size_t)rp * stride];
            bool inb = rp < eb;
            tax[0] += u.x; tay[0] += u.y;
            bax[0] += inb ? u.x : 0u; bay[0] += inb ? u.y : 0u;
        }
        unsigned bsx = 0, bsy = 0, tsx = 0, tsy = 0;
        #pragma unroll
        for (int q = 0; q < 8; ++q) { bsx += bax[q]; bsy += bay[q]; tsx += tax[q]; tsy += tay[q]; }
        bs[0] = (int)(bsx & 0xFFFFu); bs[1] = (int)(bsx >> 16);
        bs[2] = (int)(bsy & 0xFFFFu); bs[VPL - 1] = (int)(bsy >> 16);
        ts[0] = (int)(tsx & 0xFFFFu); ts[1] = (int)(tsx >> 16);
        ts[2] = (int)(tsy & 0xFFFFu); ts[VPL - 1] = (int)(tsy >> 16);
    } else {
        const unsigned short* cb = tileCnt + (size_t)b * NTe * NB + v0;
        int ba[8], taq[8];
        #pragma unroll
        for (int q = 0; q < 8; ++q) { ba[q] = 0; taq[q] = 0; }
        int rp = 0;
        for (; rp + 8 <= NTe; rp += 8) {
            #pragma unroll
            for (int q = 0; q < 8; ++q) {
                int u = (int)cb[(size_t)(rp + q) * NB];
                taq[q] += u;
                ba[q] += ((rp + q) < eb) ? u : 0;
            }
        }
        for (; rp < NTe; ++rp) {
            int u = (int)cb[(size_t)rp * NB];
            taq[0] += u;
            ba[0] += (rp < eb) ? u : 0;
        }
        #pragma unroll
        for (int q = 1; q < 8; ++q) { ba[0] += ba[q]; taq[0] += taq[q]; }
        bs[0] = ba[0]; ts[0] = taq[0];
    }

    int c[VPL], totI[VPL];
    {
        int loc = 0;
        #pragma unroll
        for (int kk = 0; kk < VPL; ++kk) { loc += bs[kk]; c[kk] = loc; }
        int incl = loc;
        #pragma unroll
        for (int off = 1; off < 64; off <<= 1) {
            int n = __shfl_up(incl, off);
            if (lane >= off) incl += n;
        }
        int excl = incl - loc;
        #pragma unroll
        for (int kk = 0; kk < VPL; ++kk) c[kk] += excl;
    }
    {
        int loc = 0;
        #pragma unroll
        for (int kk = 0; kk < VPL; ++kk) { loc += ts[kk]; totI[kk] = loc; }
        int incl = loc;
        #pragma unroll
        for (int off = 1; off < 64; off <<= 1) {
            int n = __shfl_up(incl, off);
            if (lane >= off) incl += n;
        }
        int excl = incl - loc;
        #pragma unroll
        for (int kk = 0; kk < VPL; ++kk) totI[kk] += excl;
    }
    int totLeft = __shfl_up(totI[VPL - 1], 1);
    if (lane == 0) totLeft = 0;

    const unsigned char* bi = binIdx + (size_t)b * T;

    int myLead = (lane < lead && (eb * 64 + lane) < T) ? (int)bi[eb * 64 + lane] : 0;
    for (int j = 0; j < lead; ++j) {
        int bt = __shfl(myLead, j);
        #pragma unroll
        for (int kk = 0; kk < VPL; ++kk) c[kk] += (v0 + kk >= bt) ? 1 : 0;
    }

    int t1 = min(T + 1, t0 + 16);
    bool has16 = (lane < 16) && (t0 + lane) < T;
    int   myb = has16 ? (int)bi[t0 + lane] : 0;
    float myx = has16 ? atten[(size_t)b * T + t0 + lane] : 0.0f;
    unsigned short* Fb = F + (size_t)b * (T + 1) * NB;
    float* bvb = bval + (size_t)b * T;
    for (int t = t0; t < t1; ++t) {
        unsigned short* Ft = Fb + (size_t)t * NB + v0;
        if (VPL == 4) {
            uint2 pk;
            pk.x = (unsigned)c[0] | ((unsigned)c[1] << 16);
            pk.y = (unsigned)c[2] | ((unsigned)c[VPL - 1] << 16);
            *(uint2*)Ft = pk;
        } else {
            Ft[0] = (unsigned short)c[0];
        }
        if (t < T) {
            int j = t - t0;
            int bt = __shfl(myb, j);
            float xv = __shfl(myx, j);
            int cLeft = __shfl_up(c[VPL - 1], 1);
            if (lane == 0) cLeft = 0;
            int ow  = (VPL == 4) ? (bt >> 2) : bt;
            int lc  = (VPL == 4) ? (bt & 3) : 0;
            if (lane == ow) {
                int prevc   = lc ? c[lc - 1]    : cLeft;
                int within  = c[lc] - prevc;
                int prevTot = lc ? totI[lc - 1] : totLeft;
                bvb[prevTot + within] = xv;
            }
            #pragma unroll
            for (int kk = 0; kk < VPL; ++kk) c[kk] += (v0 + kk >= bt) ? 1 : 0;
        }
    }
}

// ---------------------------------------------------------------------------
// K3: wave-per-output query. Each block recomputes sampled range + MLP
// (deterministic, identical across blocks), then 4 output-waves as in R6.
// ---------------------------------------------------------------------------
template<int NB>
__global__ void __launch_bounds__(256) k_query(
    const float* __restrict__ atten, const unsigned short* __restrict__ F,
    const float* __restrict__ bval,
    const float* __restrict__ md, const float* __restrict__ w1,
    const float* __restrict__ b1, const float* __restrict__ w2,
    const float* __restrict__ b2,
    float* __restrict__ out, int T, int n_out, int nTot)
{
    constexpr int VPL = NB / 64;
    __shared__ float sred[8];
    __shared__ int   smwi[3];
    int tid = threadIdx.x;
    int lane = tid & 63;

    float m1, m2;
    sampled_minmax_256(atten, nTot, sred, m1, m2);   // contains one __syncthreads

    if (tid < 64) {
        int samples = 0;
        if (lane < 32) {                 // lane = b*16 + j
            int b = lane >> 4, j = lane & 15;
            float acc = b1[j];
            #pragma unroll
            for (int f = 0; f < 8; ++f) acc += md[b * 8 + f] * w1[f * 16 + j];
            float h = fmaxf(acc, 0.0f);
            float p = h * w2[j];
            #pragma unroll
            for (int off = 1; off < 16; off <<= 1) p += __shfl_xor(p, off);
            float s = p + b2[0];
            float factor = 1.0f / (1.0f + expf(-s));
            float hours = 4.0f + factor * (48.0f - 4.0f);
            samples = (int)(hours * 360.0f);
        }
        #pragma unroll
        for (int off = 1; off < 64; off <<= 1) samples = max(samples, __shfl_xor(samples, off));
        int mw = min(samples, T);
        int want_even = (n_out == T + 1) ? 1 : 0;
        if ((((mw & 1) == 0) ? 1 : 0) != want_even) { if (mw < T) mw += 1; else mw -= 1; }
        if (mw < 1) mw = 1;
        if (lane == 0) { smwi[0] = mw; smwi[1] = mw >> 1; smwi[2] = (mw - 1) >> 1; }
    }
    __syncthreads();

    const int mw = smwi[0], pad = smwi[1], k = smwi[2];
    const float vmin = m1;
    const float scale = (float)NB / fmaxf(m2 - m1, 1e-10f);

    int wid = (blockIdx.x * 256 + tid) >> 6;
    if (wid >= 2 * n_out) return;
    int b = wid / n_out, o = wid - b * n_out;

    int lo_t = o - pad;
    int ta = max(lo_t, 0);
    int tb = min(lo_t + mw, T);
    int L  = ta - lo_t;
    int Rr = lo_t + mw - tb;

    const float* xb = atten + (size_t)b * T;
    float x0 = xb[0], xT = xb[T - 1];
    int b0 = bin_of(x0, vmin, scale, NB);
    int bT = bin_of(xT, vmin, scale, NB);

    const unsigned short* Fb = F + (size_t)b * (T + 1) * NB;
    int fa[VPL], fb[VPL];
    {
        const unsigned short* pa = Fb + (size_t)ta * NB + lane * VPL;
        const unsigned short* pb = Fb + (size_t)tb * NB + lane * VPL;
        if (VPL == 4) {
            uint2 ua = *(const uint2*)pa;
            fa[0] = (int)(ua.x & 0xFFFFu); fa[1] = (int)(ua.x >> 16);
            fa[2] = (int)(ua.y & 0xFFFFu); fa[VPL - 1] = (int)(ua.y >> 16);
            uint2 ub = *(const uint2*)pb;
            fb[0] = (int)(ub.x & 0xFFFFu); fb[1] = (int)(ub.x >> 16);
            fb[2] = (int)(ub.y & 0xFFFFu); fb[VPL - 1] = (int)(ub.y >> 16);
        } else {
            fa[0] = (int)pa[0]; fb[0] = (int)pb[0];
        }
    }

    int kk = k + 1;
    int w[VPL];
    #pragma unroll
    for (int j = 0; j < VPL; ++j) {
        int v = lane * VPL + j;
        w[j] = fb[j] - fa[j] + (b0 <= v ? L : 0) + (bT <= v ? Rr : 0);
    }
    unsigned long long m = __ballot(w[VPL - 1] >= kk);
    int ll = (int)__ffsll(m) - 1;

    int wj[VPL], faj[VPL], fbj[VPL];
    #pragma unroll
    for (int j = 0; j < VPL; ++j) {
        wj[j]  = __shfl(w[j], ll);
        faj[j] = __shfl(fa[j], ll);
        fbj[j] = __shfl(fb[j], ll);
    }
    int wprevL  = __shfl(w[VPL - 1], ll - 1);
    int faPrevL = __shfl(fa[VPL - 1], ll - 1);
    int fbPrevL = __shfl(fb[VPL - 1], ll - 1);
    if (ll == 0) { wprevL = 0; faPrevL = 0; fbPrevL = 0; }

    int jj = VPL - 1;
    #pragma unroll
    for (int j = VPL - 1; j >= 0; --j) if (wj[j] >= kk) jj = j;
    int bsel = ll * VPL + jj;
    int wprev = jj > 0 ? wj[jj - 1] : wprevL;
    int faSel = faj[jj], fbSel = fbj[jj];
    int pA = jj > 0 ? faj[jj - 1] : faPrevL;
    int pB = jj > 0 ? fbj[jj - 1] : fbPrevL;

    int kp = k - wprev;
    int withinA = faSel - pA;
    int cntw = (fbSel - pB) - withinA;
    int s0 = bsel ? (int)Fb[(size_t)T * NB + bsel - 1] : 0;
    int j0 = s0 + withinA;
    int j1e = j0 + cntw;

    int Lc = (b0 == bsel) ? L : 0;
    int Rc = (bT == bsel) ? Rr : 0;

    const float* bv = bval + (size_t)b * T;

    const int CAND = 4;
    float rr[CAND];
    bool reg = (cntw <= 64 * CAND);
    float cmin = 3.0e38f, cmax = -3.0e38f;
    if (reg) {
        #pragma unroll
        for (int q = 0; q < CAND; ++q) {
            int idx = j0 + lane + q * 64;
            if (idx < j1e) {
                float v = bv[idx];
                rr[q] = v;
                cmin = fminf(cmin, v); cmax = fmaxf(cmax, v);
            } else {
                rr[q] = 3.0e38f;
            }
        }
    } else {
        for (int j = j0 + lane; j < j1e; j += 64) {
            float v = bv[j];
            cmin = fminf(cmin, v); cmax = fmaxf(cmax, v);
        }
    }
    #pragma unroll
    for (int off = 1; off < 64; off <<= 1) {
        cmin = fminf(cmin, __shfl_xor(cmin, off));
        cmax = fmaxf(cmax, __shfl_xor(cmax, off));
    }
    if (Lc > 0) { cmin = fminf(cmin, x0); cmax = fmaxf(cmax, x0); }
    if (Rc > 0) { cmin = fminf(cmin, xT); cmax = fmaxf(cmax, xT); }

    float vlo = cmin, vhi = cmax;
    int need = kp + 1;
    for (int it = 0; it < 14; ++it) {
        float vm = 0.5f * (vlo + vhi);
        int cnt = ((x0 < vm) ? Lc : 0) + ((xT < vm) ? Rc : 0);
        if (reg) {
            #pragma unroll
            for (int q = 0; q < CAND; ++q)
                cnt += __popcll(__ballot(rr[q] < vm));
        } else {
            int my = 0;
            for (int j = j0 + lane; j < j1e; j += 64) my += (bv[j] < vm) ? 1 : 0;
            #pragma unroll
            for (int off = 1; off < 64; off <<= 1) my += __shfl_xor(my, off);
            cnt += my;
        }
        if (cnt >= need) vhi = vm; else vlo = vm;
    }
    if (lane == 0) out[(size_t)b * n_out + o] = 0.5f * (vlo + vhi);
}

// ---------------------------------------------------------------------------
// Fallback (tiny d_ws): wave-per-output bisection, window min/max bracket.
// Self-contained (computes MLP per block).
// ---------------------------------------------------------------------------
__global__ void __launch_bounds__(256) k_fallback(
    const float* __restrict__ atten,
    const float* __restrict__ md, const float* __restrict__ w1,
    const float* __restrict__ b1, const float* __restrict__ w2,
    const float* __restrict__ b2,
    float* __restrict__ out, int T, int n_out)
{
    __shared__ int smwi[3];
    int tid = threadIdx.x;
    int wave = tid >> 6;
    int lane = tid & 63;
    if (tid < 64) {
        int samples = 0;
        if (lane < 32) {
            int b = lane >> 4, j = lane & 15;
            float acc = b1[j];
            #pragma unroll
            for (int f = 0; f < 8; ++f) acc += md[b * 8 + f] * w1[f * 16 + j];
            float h = fmaxf(acc, 0.0f);
            float p = h * w2[j];
            #pragma unroll
            for (int off = 1; off < 16; off <<= 1) p += __shfl_xor(p, off);
            float s = p + b2[0];
            float factor = 1.0f / (1.0f + expf(-s));
            float hours = 4.0f + factor * (48.0f - 4.0f);
            samples = (int)(hours * 360.0f);
        }
        #pragma unroll
        for (int off = 1; off < 64; off <<= 1) samples = max(samples, __shfl_xor(samples, off));
        int mw = min(samples, T);
        int want_even = (n_out == T + 1) ? 1 : 0;
        if ((((mw & 1) == 0) ? 1 : 0) != want_even) { if (mw < T) mw += 1; else mw -= 1; }
        if (mw < 1) mw = 1;
        if (lane == 0) { smwi[0] = mw; smwi[1] = mw >> 1; smwi[2] = (mw - 1) >> 1; }
    }
    __syncthreads();
    int mw = smwi[0], pad = smwi[1], k = smwi[2];

    int gid = blockIdx.x * 4 + wave;
    if (gid >= 2 * n_out) return;
    int b = gid / n_out;
    int o = gid - b * n_out;
    const float* xb = atten + (size_t)b * T;
    int lo_t = o - pad;
    float lo = 3.0e38f, hi = -3.0e38f;
    for (int i = lane; i < mw; i += 64) {
        int t = lo_t + i;
        t = t < 0 ? 0 : (t >= T ? T - 1 : t);
        float x = xb[t];
        lo = fminf(lo, x); hi = fmaxf(hi, x);
    }
    #pragma unroll
    for (int off = 1; off < 64; off <<= 1) {
        lo = fminf(lo, __shfl_xor(lo, off));
        hi = fmaxf(hi, __shfl_xor(hi, off));
    }
    for (int it = 0; it < 26; ++it) {
        float vm = 0.5f * (lo + hi);
        int c = 0;
        for (int i = lane; i < mw; i += 64) {
            int t = lo_t + i;
            t = t < 0 ? 0 : (t >= T ? T - 1 : t);
            c += (xb[t] < vm) ? 1 : 0;
        }
        #pragma unroll
        for (int off = 1; off < 64; off <<= 1) c += __shfl_xor(c, off);
        if (c >= k + 1) hi = vm; else lo = vm;
    }
    if (lane == 0) out[(size_t)b * n_out + o] = 0.5f * (lo + hi);
}

// ---------------------------------------------------------------------------
struct Plan { size_t oBin, oCnt, oF, oV, total; };
static Plan make_plan(int NB, int nTot, int T, int NTe) {
    auto a64 = [](size_t x) { return (x + 63) & ~(size_t)63; };
    Plan p;
    size_t off = 64;
    p.oBin = off; off = a64(off + (size_t)nTot);
    p.oCnt = off; off = a64(off + (size_t)2 * NTe * NB * 2);
    p.oF   = off; off = a64(off + (size_t)2 * (T + 1) * NB * 2);
    p.oV   = off; off = a64(off + (size_t)nTot * 4);
    p.total = off;
    return p;
}

template<int NB>
static void run_pipeline(const float* atten, const float* md,
                         const float* w1, const float* b1,
                         const float* w2, const float* b2,
                         char* ws, const Plan& p, float* out,
                         int T, int n_out, int nTot, int NTe,
                         hipStream_t stream)
{
    unsigned char*  binIdx  = (unsigned char*)(ws + p.oBin);
    unsigned short* tileCnt = (unsigned short*)(ws + p.oCnt);
    unsigned short* F       = (unsigned short*)(ws + p.oF);
    float*          bval    = (float*)(ws + p.oV);
    int NTr16 = (T + 1 + 15) / 16;

    int histBlocks = (2 * NTe + 3) / 4;
    k_hist<NB><<<dim3(histBlocks), dim3(256), 0, stream>>>(
        atten, binIdx, tileCnt, T, NTe, nTot);
    k_cdf_scatter<NB><<<dim3(2 * NTr16), dim3(64), 0, stream>>>(
        binIdx, tileCnt, atten, F, bval, T, NTe, NTr16);
    int nWaves = 2 * n_out;
    k_query<NB><<<dim3((nWaves + 3) / 4), dim3(256), 0, stream>>>(
        atten, F, bval, md, w1, b1, w2, b2, out, T, n_out, nTot);
}

extern "C" void kernel_launch(void* const* d_in, const int* in_sizes, int n_in,
                              void* d_out, int out_size, void* d_ws, size_t ws_size,
                              hipStream_t stream)
{
    const float* atten = (const float*)d_in[0];
    const float* md    = (const float*)d_in[1];
    const float* w1    = (const float*)d_in[2];
    const float* b1    = (const float*)d_in[3];
    const float* w2    = (const float*)d_in[4];
    const float* b2    = (const float*)d_in[5];
    float* out = (float*)d_out;

    const int B = 2;
    const int nTot  = in_sizes[0];
    const int T     = nTot / B;
    const int n_out = out_size / B;
    const int NTe = (T + 63) / 64;

    char* ws = (char*)d_ws;

    Plan p256 = make_plan(256, nTot, T, NTe);
    Plan p64  = make_plan(64,  nTot, T, NTe);
    if (ws_size >= p256.total) {
        run_pipeline<256>(atten, md, w1, b1, w2, b2, ws, p256, out,
                          T, n_out, nTot, NTe, stream);
    } else if (ws_size >= p64.total) {
        run_pipeline<64>(atten, md, w1, b1, w2, b2, ws, p64, out,
                         T, n_out, nTot, NTe, stream);
    } else {
        int blocks = (2 * n_out + 3) / 4;
        k_fallback<<<dim3(blocks), dim3(256), 0, stream>>>(
            atten, md, w1, b1, w2, b2, out, T, n_out);
    }
}

// Round 9
// 102.878 us; speedup vs baseline: 4.1314x; 1.0632x over previous
//
#include <hip/hip_runtime.h>
#include <math.h>

// ws header: hdr_i[0]=mw, hdr_i[1]=pad, hdr_i[2]=midx(k), hdr_f[3]=smin, hdr_f[4]=smax
// LESSON (R7): cooperative grid.sync() costs ~100us/barrier on MI355X — kernel
// boundaries are the cheap barrier. LESSON (R8): redundant per-block setup
// recompute (sample+MLP prologue in 339 blocks) costs more than a 1us setup node.

__device__ __forceinline__ int bin_of(float x, float vmin, float scale, int NB) {
    int v = (int)((x - vmin) * scale);
    return v < 0 ? 0 : (v > NB - 1 ? NB - 1 : v);
}

// ---------------------------------------------------------------------------
// K1: sampled min/max (1024 strided points) + tiny MLP. One 256-thr block.
// Sampled range is safe: binning is a monotone clamped map (rank-exact);
// the final bisection brackets from actual candidate values.
// ---------------------------------------------------------------------------
__global__ void __launch_bounds__(256) k_setup(
    const float* __restrict__ atten, const float* __restrict__ md,
    const float* __restrict__ w1, const float* __restrict__ b1,
    const float* __restrict__ w2, const float* __restrict__ b2,
    int* __restrict__ hdr_i, float* __restrict__ hdr_f,
    int T, int n_out, int nTot)
{
    __shared__ float smin[4], smax[4];
    int tid = threadIdx.x;
    int strideS = nTot >> 10; if (strideS < 1) strideS = 1;
    float vmin = 3.0e38f, vmax = -3.0e38f;
    #pragma unroll
    for (int q = 0; q < 4; ++q) {
        int idx = (tid + q * 256) * strideS;
        if (idx < nTot) {
            float x = atten[idx];
            vmin = fminf(vmin, x); vmax = fmaxf(vmax, x);
        }
    }
    #pragma unroll
    for (int off = 1; off < 64; off <<= 1) {
        vmin = fminf(vmin, __shfl_xor(vmin, off));
        vmax = fmaxf(vmax, __shfl_xor(vmax, off));
    }
    if ((tid & 63) == 0) { smin[tid >> 6] = vmin; smax[tid >> 6] = vmax; }
    __syncthreads();
    if (tid < 64) {
        int lane = tid;
        float m1 = (lane < 4) ? smin[lane] : 3.0e38f;
        float m2 = (lane < 4) ? smax[lane] : -3.0e38f;
        #pragma unroll
        for (int off = 1; off < 4; off <<= 1) {
            m1 = fminf(m1, __shfl_xor(m1, off));
            m2 = fmaxf(m2, __shfl_xor(m2, off));
        }
        int samples = 0;
        if (lane < 32) {                 // lane = b*16 + j
            int b = lane >> 4, j = lane & 15;
            float acc = b1[j];
            #pragma unroll
            for (int f = 0; f < 8; ++f) acc += md[b * 8 + f] * w1[f * 16 + j];
            float h = fmaxf(acc, 0.0f);
            float p = h * w2[j];
            #pragma unroll
            for (int off = 1; off < 16; off <<= 1) p += __shfl_xor(p, off);
            float s = p + b2[0];
            float factor = 1.0f / (1.0f + expf(-s));
            float hours = 4.0f + factor * (48.0f - 4.0f);
            samples = (int)(hours * 360.0f);
        }
        #pragma unroll
        for (int off = 1; off < 64; off <<= 1) samples = max(samples, __shfl_xor(samples, off));
        int mw = min(samples, T);
        // snap parity to harness-fixed n_out (guards float roundoff)
        int want_even = (n_out == T + 1) ? 1 : 0;
        if ((((mw & 1) == 0) ? 1 : 0) != want_even) { if (mw < T) mw += 1; else mw -= 1; }
        if (mw < 1) mw = 1;
        if (lane == 0) {
            hdr_i[0] = mw; hdr_i[1] = mw >> 1; hdr_i[2] = (mw - 1) >> 1;
            hdr_f[3] = m1; hdr_f[4] = m2;
        }
    }
}

// ---------------------------------------------------------------------------
// K2: binning + per-tile histogram. 4 element-tiles per 256-thr block,
// wave-private LDS hist (no block syncs needed).
// ---------------------------------------------------------------------------
template<int NB>
__global__ void __launch_bounds__(256) k_hist(
    const float* __restrict__ atten, unsigned char* __restrict__ binIdx,
    unsigned short* __restrict__ tileCnt, const float* __restrict__ hdr_f,
    int T, int NTe)
{
    __shared__ unsigned int hist[4][NB];
    int wave = threadIdx.x >> 6;
    int lane = threadIdx.x & 63;
    int g = blockIdx.x * 4 + wave;
    bool valid = g < 2 * NTe;
    int b = g / NTe, tile = g - b * NTe;

    unsigned int* h = hist[wave];          // wave-private: no __syncthreads
    #pragma unroll
    for (int j = lane; j < NB; j += 64) h[j] = 0u;

    int t = tile * 64 + lane;
    if (valid && t < T) {
        float vmin = hdr_f[3], vmax = hdr_f[4];
        float scale = (float)NB / fmaxf(vmax - vmin, 1e-10f);
        float x = atten[(size_t)b * T + t];
        int v = bin_of(x, vmin, scale, NB);
        binIdx[(size_t)b * T + t] = (unsigned char)v;
        atomicAdd(&h[v], 1u);
    }
    if (valid) {
        unsigned short* row = tileCnt + ((size_t)b * NTe + tile) * NB;
        #pragma unroll
        for (int j = lane; j < NB; j += 64) row[j] = (unsigned short)h[j];
    }
}

// ---------------------------------------------------------------------------
// K3: fused CDF writer + counting-sort scatter. 16-record tiles, 64 thr.
// ILP-8 packed-u16 prefix (R5 fix); dual base/totals accumulators (R6).
// ---------------------------------------------------------------------------
template<int NB>
__global__ void __launch_bounds__(64) k_cdf_scatter(
    const unsigned char* __restrict__ binIdx, const unsigned short* __restrict__ tileCnt,
    const float* __restrict__ atten,
    unsigned short* __restrict__ F, float* __restrict__ bval,
    int T, int NTe, int NTr16)
{
    constexpr int VPL = NB / 64;
    int blk = blockIdx.x;
    int b = blk / NTr16, r = blk - b * NTr16;
    int lane = threadIdx.x;
    int v0 = lane * VPL;
    int t0 = r * 16;
    int eb = t0 >> 6;
    int lead = t0 & 63;

    int bs[VPL], ts[VPL];
    if (VPL == 4) {
        const uint2* cb2 = (const uint2*)(tileCnt + (size_t)b * NTe * NB) + lane;
        const int stride = NB / 4;
        unsigned bax[8], bay[8], tax[8], tay[8];
        #pragma unroll
        for (int q = 0; q < 8; ++q) { bax[q] = bay[q] = tax[q] = tay[q] = 0u; }
        int rp = 0;
        for (; rp + 8 <= NTe; rp += 8) {
            #pragma unroll
            for (int q = 0; q < 8; ++q) {
                uint2 u = cb2[(size_t)(rp + q) * stride];
                bool inb = (rp + q) < eb;
                tax[q] += u.x; tay[q] += u.y;
                bax[q] += inb ? u.x : 0u; bay[q] += inb ? u.y : 0u;
            }
        }
        for (; rp < NTe; ++rp) {
            uint2 u = cb2[(size_t)rp * stride];
            bool inb = rp < eb;
            tax[0] += u.x; tay[0] += u.y;
            bax[0] += inb ? u.x : 0u; bay[0] += inb ? u.y : 0u;
        }
        unsigned bsx = 0, bsy = 0, tsx = 0, tsy = 0;
        #pragma unroll
        for (int q = 0; q < 8; ++q) { bsx += bax[q]; bsy += bay[q]; tsx += tax[q]; tsy += tay[q]; }
        bs[0] = (int)(bsx & 0xFFFFu); bs[1] = (int)(bsx >> 16);
        bs[2] = (int)(bsy & 0xFFFFu); bs[VPL - 1] = (int)(bsy >> 16);
        ts[0] = (int)(tsx & 0xFFFFu); ts[1] = (int)(tsx >> 16);
        ts[2] = (int)(tsy & 0xFFFFu); ts[VPL - 1] = (int)(tsy >> 16);
    } else {
        const unsigned short* cb = tileCnt + (size_t)b * NTe * NB + v0;
        int ba[8], taq[8];
        #pragma unroll
        for (int q = 0; q < 8; ++q) { ba[q] = 0; taq[q] = 0; }
        int rp = 0;
        for (; rp + 8 <= NTe; rp += 8) {
            #pragma unroll
            for (int q = 0; q < 8; ++q) {
                int u = (int)cb[(size_t)(rp + q) * NB];
                taq[q] += u;
                ba[q] += ((rp + q) < eb) ? u : 0;
            }
        }
        for (; rp < NTe; ++rp) {
            int u = (int)cb[(size_t)rp * NB];
            taq[0] += u;
            ba[0] += (rp < eb) ? u : 0;
        }
        #pragma unroll
        for (int q = 1; q < 8; ++q) { ba[0] += ba[q]; taq[0] += taq[q]; }
        bs[0] = ba[0]; ts[0] = taq[0];
    }

    int c[VPL], totI[VPL];
    {
        int loc = 0;
        #pragma unroll
        for (int kk = 0; kk < VPL; ++kk) { loc += bs[kk]; c[kk] = loc; }
        int incl = loc;
        #pragma unroll
        for (int off = 1; off < 64; off <<= 1) {
            int n = __shfl_up(incl, off);
            if (lane >= off) incl += n;
        }
        int excl = incl - loc;
        #pragma unroll
        for (int kk = 0; kk < VPL; ++kk) c[kk] += excl;
    }
    {
        int loc = 0;
        #pragma unroll
        for (int kk = 0; kk < VPL; ++kk) { loc += ts[kk]; totI[kk] = loc; }
        int incl = loc;
        #pragma unroll
        for (int off = 1; off < 64; off <<= 1) {
            int n = __shfl_up(incl, off);
            if (lane >= off) incl += n;
        }
        int excl = incl - loc;
        #pragma unroll
        for (int kk = 0; kk < VPL; ++kk) totI[kk] += excl;
    }
    int totLeft = __shfl_up(totI[VPL - 1], 1);
    if (lane == 0) totLeft = 0;

    const unsigned char* bi = binIdx + (size_t)b * T;

    int myLead = (lane < lead && (eb * 64 + lane) < T) ? (int)bi[eb * 64 + lane] : 0;
    for (int j = 0; j < lead; ++j) {
        int bt = __shfl(myLead, j);
        #pragma unroll
        for (int kk = 0; kk < VPL; ++kk) c[kk] += (v0 + kk >= bt) ? 1 : 0;
    }

    int t1 = min(T + 1, t0 + 16);
    bool has16 = (lane < 16) && (t0 + lane) < T;
    int   myb = has16 ? (int)bi[t0 + lane] : 0;
    float myx = has16 ? atten[(size_t)b * T + t0 + lane] : 0.0f;
    unsigned short* Fb = F + (size_t)b * (T + 1) * NB;
    float* bvb = bval + (size_t)b * T;
    for (int t = t0; t < t1; ++t) {
        unsigned short* Ft = Fb + (size_t)t * NB + v0;
        if (VPL == 4) {
            uint2 pk;
            pk.x = (unsigned)c[0] | ((unsigned)c[1] << 16);
            pk.y = (unsigned)c[2] | ((unsigned)c[VPL - 1] << 16);
            *(uint2*)Ft = pk;
        } else {
            Ft[0] = (unsigned short)c[0];
        }
        if (t < T) {
            int j = t - t0;
            int bt = __shfl(myb, j);
            float xv = __shfl(myx, j);
            int cLeft = __shfl_up(c[VPL - 1], 1);
            if (lane == 0) cLeft = 0;
            int ow  = (VPL == 4) ? (bt >> 2) : bt;
            int lc  = (VPL == 4) ? (bt & 3) : 0;
            if (lane == ow) {
                int prevc   = lc ? c[lc - 1]    : cLeft;
                int within  = c[lc] - prevc;
                int prevTot = lc ? totI[lc - 1] : totLeft;
                bvb[prevTot + within] = xv;
            }
            #pragma unroll
            for (int kk = 0; kk < VPL; ++kk) c[kk] += (v0 + kk >= bt) ? 1 : 0;
        }
    }
}

// ---------------------------------------------------------------------------
// K4: wave-per-output query. F rows coalesced, ballot bin-select, register
// candidates, bracket from actual candidate min/max, ballot bisection.
// ---------------------------------------------------------------------------
template<int NB>
__global__ void __launch_bounds__(256) k_query(
    const float* __restrict__ atten, const unsigned short* __restrict__ F,
    const float* __restrict__ bval,
    const int* __restrict__ hdr_i, const float* __restrict__ hdr_f,
    float* __restrict__ out, int T, int n_out)
{
    constexpr int VPL = NB / 64;
    int wid = (blockIdx.x * 256 + threadIdx.x) >> 6;
    int lane = threadIdx.x & 63;
    if (wid >= 2 * n_out) return;
    int b = wid / n_out, o = wid - b * n_out;

    int mw = hdr_i[0], pad = hdr_i[1], k = hdr_i[2];
    float vmin = hdr_f[3], vmax = hdr_f[4];
    float scale = (float)NB / fmaxf(vmax - vmin, 1e-10f);

    int lo_t = o - pad;
    int ta = max(lo_t, 0);
    int tb = min(lo_t + mw, T);
    int L  = ta - lo_t;
    int Rr = lo_t + mw - tb;

    const float* xb = atten + (size_t)b * T;
    float x0 = xb[0], xT = xb[T - 1];
    int b0 = bin_of(x0, vmin, scale, NB);
    int bT = bin_of(xT, vmin, scale, NB);

    const unsigned short* Fb = F + (size_t)b * (T + 1) * NB;
    int fa[VPL], fb[VPL];
    {
        const unsigned short* pa = Fb + (size_t)ta * NB + lane * VPL;
        const unsigned short* pb = Fb + (size_t)tb * NB + lane * VPL;
        if (VPL == 4) {
            uint2 ua = *(const uint2*)pa;
            fa[0] = (int)(ua.x & 0xFFFFu); fa[1] = (int)(ua.x >> 16);
            fa[2] = (int)(ua.y & 0xFFFFu); fa[VPL - 1] = (int)(ua.y >> 16);
            uint2 ub = *(const uint2*)pb;
            fb[0] = (int)(ub.x & 0xFFFFu); fb[1] = (int)(ub.x >> 16);
            fb[2] = (int)(ub.y & 0xFFFFu); fb[VPL - 1] = (int)(ub.y >> 16);
        } else {
            fa[0] = (int)pa[0]; fb[0] = (int)pb[0];
        }
    }

    int kk = k + 1;
    int w[VPL];
    #pragma unroll
    for (int j = 0; j < VPL; ++j) {
        int v = lane * VPL + j;
        w[j] = fb[j] - fa[j] + (b0 <= v ? L : 0) + (bT <= v ? Rr : 0);
    }
    unsigned long long m = __ballot(w[VPL - 1] >= kk);
    int ll = (int)__ffsll(m) - 1;

    int wj[VPL], faj[VPL], fbj[VPL];
    #pragma unroll
    for (int j = 0; j < VPL; ++j) {
        wj[j]  = __shfl(w[j], ll);
        faj[j] = __shfl(fa[j], ll);
        fbj[j] = __shfl(fb[j], ll);
    }
    int wprevL  = __shfl(w[VPL - 1], ll - 1);
    int faPrevL = __shfl(fa[VPL - 1], ll - 1);
    int fbPrevL = __shfl(fb[VPL - 1], ll - 1);
    if (ll == 0) { wprevL = 0; faPrevL = 0; fbPrevL = 0; }

    int jj = VPL - 1;
    #pragma unroll
    for (int j = VPL - 1; j >= 0; --j) if (wj[j] >= kk) jj = j;
    int bsel = ll * VPL + jj;
    int wprev = jj > 0 ? wj[jj - 1] : wprevL;
    int faSel = faj[jj], fbSel = fbj[jj];
    int pA = jj > 0 ? faj[jj - 1] : faPrevL;
    int pB = jj > 0 ? fbj[jj - 1] : fbPrevL;

    int kp = k - wprev;
    int withinA = faSel - pA;
    int cntw = (fbSel - pB) - withinA;
    int s0 = bsel ? (int)Fb[(size_t)T * NB + bsel - 1] : 0;
    int j0 = s0 + withinA;
    int j1e = j0 + cntw;

    int Lc = (b0 == bsel) ? L : 0;
    int Rc = (bT == bsel) ? Rr : 0;

    const float* bv = bval + (size_t)b * T;

    const int CAND = 4;
    float rr[CAND];
    bool reg = (cntw <= 64 * CAND);
    float cmin = 3.0e38f, cmax = -3.0e38f;
    if (reg) {
        #pragma unroll
        for (int q = 0; q < CAND; ++q) {
            int idx = j0 + lane + q * 64;
            if (idx < j1e) {
                float v = bv[idx];
                rr[q] = v;
                cmin = fminf(cmin, v); cmax = fmaxf(cmax, v);
            } else {
                rr[q] = 3.0e38f;
            }
        }
    } else {
        for (int j = j0 + lane; j < j1e; j += 64) {
            float v = bv[j];
            cmin = fminf(cmin, v); cmax = fmaxf(cmax, v);
        }
    }
    #pragma unroll
    for (int off = 1; off < 64; off <<= 1) {
        cmin = fminf(cmin, __shfl_xor(cmin, off));
        cmax = fmaxf(cmax, __shfl_xor(cmax, off));
    }
    if (Lc > 0) { cmin = fminf(cmin, x0); cmax = fmaxf(cmax, x0); }
    if (Rc > 0) { cmin = fminf(cmin, xT); cmax = fmaxf(cmax, xT); }

    float vlo = cmin, vhi = cmax;
    int need = kp + 1;
    for (int it = 0; it < 14; ++it) {
        float vm = 0.5f * (vlo + vhi);
        int cnt = ((x0 < vm) ? Lc : 0) + ((xT < vm) ? Rc : 0);
        if (reg) {
            #pragma unroll
            for (int q = 0; q < CAND; ++q)
                cnt += __popcll(__ballot(rr[q] < vm));
        } else {
            int my = 0;
            for (int j = j0 + lane; j < j1e; j += 64) my += (bv[j] < vm) ? 1 : 0;
            #pragma unroll
            for (int off = 1; off < 64; off <<= 1) my += __shfl_xor(my, off);
            cnt += my;
        }
        if (cnt >= need) vhi = vm; else vlo = vm;
    }
    if (lane == 0) out[(size_t)b * n_out + o] = 0.5f * (vlo + vhi);
}

// ---------------------------------------------------------------------------
// Fallback (tiny d_ws): self-contained wave-per-output bisection.
// ---------------------------------------------------------------------------
__global__ void __launch_bounds__(256) k_fallback(
    const float* __restrict__ atten,
    const float* __restrict__ md, const float* __restrict__ w1,
    const float* __restrict__ b1, const float* __restrict__ w2,
    const float* __restrict__ b2,
    float* __restrict__ out, int T, int n_out)
{
    __shared__ int smwi[3];
    int tid = threadIdx.x;
    int wave = tid >> 6;
    int lane = tid & 63;
    if (tid < 64) {
        int samples = 0;
        if (lane < 32) {
            int b = lane >> 4, j = lane & 15;
            float acc = b1[j];
            #pragma unroll
            for (int f = 0; f < 8; ++f) acc += md[b * 8 + f] * w1[f * 16 + j];
            float h = fmaxf(acc, 0.0f);
            float p = h * w2[j];
            #pragma unroll
            for (int off = 1; off < 16; off <<= 1) p += __shfl_xor(p, off);
            float s = p + b2[0];
            float factor = 1.0f / (1.0f + expf(-s));
            float hours = 4.0f + factor * (48.0f - 4.0f);
            samples = (int)(hours * 360.0f);
        }
        #pragma unroll
        for (int off = 1; off < 64; off <<= 1) samples = max(samples, __shfl_xor(samples, off));
        int mw = min(samples, T);
        int want_even = (n_out == T + 1) ? 1 : 0;
        if ((((mw & 1) == 0) ? 1 : 0) != want_even) { if (mw < T) mw += 1; else mw -= 1; }
        if (mw < 1) mw = 1;
        if (lane == 0) { smwi[0] = mw; smwi[1] = mw >> 1; smwi[2] = (mw - 1) >> 1; }
    }
    __syncthreads();
    int mw = smwi[0], pad = smwi[1], k = smwi[2];

    int gid = blockIdx.x * 4 + wave;
    if (gid >= 2 * n_out) return;
    int b = gid / n_out;
    int o = gid - b * n_out;
    const float* xb = atten + (size_t)b * T;
    int lo_t = o - pad;
    float lo = 3.0e38f, hi = -3.0e38f;
    for (int i = lane; i < mw; i += 64) {
        int t = lo_t + i;
        t = t < 0 ? 0 : (t >= T ? T - 1 : t);
        float x = xb[t];
        lo = fminf(lo, x); hi = fmaxf(hi, x);
    }
    #pragma unroll
    for (int off = 1; off < 64; off <<= 1) {
        lo = fminf(lo, __shfl_xor(lo, off));
        hi = fmaxf(hi, __shfl_xor(hi, off));
    }
    for (int it = 0; it < 26; ++it) {
        float vm = 0.5f * (lo + hi);
        int c = 0;
        for (int i = lane; i < mw; i += 64) {
            int t = lo_t + i;
            t = t < 0 ? 0 : (t >= T ? T - 1 : t);
            c += (xb[t] < vm) ? 1 : 0;
        }
        #pragma unroll
        for (int off = 1; off < 64; off <<= 1) c += __shfl_xor(c, off);
        if (c >= k + 1) hi = vm; else lo = vm;
    }
    if (lane == 0) out[(size_t)b * n_out + o] = 0.5f * (lo + hi);
}

// ---------------------------------------------------------------------------
struct Plan { size_t oBin, oCnt, oF, oV, total; };
static Plan make_plan(int NB, int nTot, int T, int NTe) {
    auto a64 = [](size_t x) { return (x + 63) & ~(size_t)63; };
    Plan p;
    size_t off = 64;
    p.oBin = off; off = a64(off + (size_t)nTot);
    p.oCnt = off; off = a64(off + (size_t)2 * NTe * NB * 2);
    p.oF   = off; off = a64(off + (size_t)2 * (T + 1) * NB * 2);
    p.oV   = off; off = a64(off + (size_t)nTot * 4);
    p.total = off;
    return p;
}

template<int NB>
static void run_pipeline(const float* atten, const float* md,
                         const float* w1, const float* b1,
                         const float* w2, const float* b2,
                         char* ws, const Plan& p,
                         int* hdr_i, float* hdr_f, float* out,
                         int T, int n_out, int nTot, int NTe,
                         hipStream_t stream)
{
    unsigned char*  binIdx  = (unsigned char*)(ws + p.oBin);
    unsigned short* tileCnt = (unsigned short*)(ws + p.oCnt);
    unsigned short* F       = (unsigned short*)(ws + p.oF);
    float*          bval    = (float*)(ws + p.oV);
    int NTr16 = (T + 1 + 15) / 16;

    k_setup<<<dim3(1), dim3(256), 0, stream>>>(atten, md, w1, b1, w2, b2,
                                               hdr_i, hdr_f, T, n_out, nTot);
    int histBlocks = (2 * NTe + 3) / 4;
    k_hist<NB><<<dim3(histBlocks), dim3(256), 0, stream>>>(
        atten, binIdx, tileCnt, hdr_f, T, NTe);
    k_cdf_scatter<NB><<<dim3(2 * NTr16), dim3(64), 0, stream>>>(
        binIdx, tileCnt, atten, F, bval, T, NTe, NTr16);
    int nWaves = 2 * n_out;
    k_query<NB><<<dim3((nWaves + 3) / 4), dim3(256), 0, stream>>>(
        atten, F, bval, hdr_i, hdr_f, out, T, n_out);
}

extern "C" void kernel_launch(void* const* d_in, const int* in_sizes, int n_in,
                              void* d_out, int out_size, void* d_ws, size_t ws_size,
                              hipStream_t stream)
{
    const float* atten = (const float*)d_in[0];
    const float* md    = (const float*)d_in[1];
    const float* w1    = (const float*)d_in[2];
    const float* b1    = (const float*)d_in[3];
    const float* w2    = (const float*)d_in[4];
    const float* b2    = (const float*)d_in[5];
    float* out = (float*)d_out;

    const int B = 2;
    const int nTot  = in_sizes[0];
    const int T     = nTot / B;
    const int n_out = out_size / B;
    const int NTe = (T + 63) / 64;

    char* ws = (char*)d_ws;
    int*   hdr_i = (int*)ws;
    float* hdr_f = (float*)ws;

    Plan p256 = make_plan(256, nTot, T, NTe);
    Plan p64  = make_plan(64,  nTot, T, NTe);
    if (ws_size >= p256.total) {
        run_pipeline<256>(atten, md, w1, b1, w2, b2, ws, p256, hdr_i, hdr_f, out,
                          T, n_out, nTot, NTe, stream);
    } else if (ws_size >= p64.total) {
        run_pipeline<64>(atten, md, w1, b1, w2, b2, ws, p64, hdr_i, hdr_f, out,
                         T, n_out, nTot, NTe, stream);
    } else {
        int blocks = (2 * n_out + 3) / 4;
        k_fallback<<<dim3(blocks), dim3(256), 0, stream>>>(
            atten, md, w1, b1, w2, b2, out, T, n_out);
    }
}